// Round 8
// baseline (84.310 us; speedup 1.0000x reference)
//
#include <hip/hip_runtime.h>
#include <stdint.h>

#define NB 8
#define NN 49104
#define NC 90
#define NK 1000
#define SA 192        // anchors per score block
#define NSEG 256      // score blocks (= key segments) per image
#define NTH 768       // threads per block (score: 4/anchor; worker: all phases)
#define CAP 6912      // worker candidate capacity (expected ~4224, 43 sigma)
#define NB2 4352      // 4-ULP-wide score bins
#define HISTN 5376    // 768*7 chunk-7 scan domain (bins >= NB2 stay zero)
#define NWORK 8

typedef unsigned long long u64;

// Agent-scope relaxed atomics: sc1 route (bypass non-coherent per-XCD L2).
// NO release/acquire anywhere -> no buffer_wbl2 (the r3 disaster).
__device__ __forceinline__ u64 aload64(const u64* p) {
  return __hip_atomic_load(p, __ATOMIC_RELAXED, __HIP_MEMORY_SCOPE_AGENT);
}
__device__ __forceinline__ void astore64(u64* p, u64 v) {
  __hip_atomic_store(p, v, __ATOMIC_RELAXED, __HIP_MEMORY_SCOPE_AGENT);
}
__device__ __forceinline__ unsigned aload32(const unsigned* p) {
  return __hip_atomic_load(p, __ATOMIC_RELAXED, __HIP_MEMORY_SCOPE_AGENT);
}
__device__ __forceinline__ void astore32(unsigned* p, unsigned v) {
  __hip_atomic_store(p, v, __ATOMIC_RELAXED, __HIP_MEMORY_SCOPE_AGENT);
}

__device__ __forceinline__ void decode_box(const float4 rg, const float4 an,
                                           float W, float H, float* out) {
#pragma clang fp contract(off)
  float l = an.x, t = an.y, r = an.z, bo = an.w;
  float wa = r - l, ha = bo - t;
  float cxa = l + wa * 0.5f, cya = t + ha * 0.5f;
  float cx = cxa + rg.x * wa;
  float cy = cya + rg.y * ha;
  float w = wa * expf(rg.z);
  float h = ha * expf(rg.w);
  float left = cx - w * 0.5f, top = cy - h * 0.5f;
  float right = left + w, botm = top + h;
  out[0] = fminf(fmaxf(left, 0.f), W - 1.f);
  out[1] = fminf(fmaxf(top, 0.f), H - 1.f);
  out[2] = fminf(fmaxf(right, 0.f), W - 1.f);
  out[3] = fminf(fmaxf(botm, 0.f), H - 1.f);
}

// ---- single mega-kernel: score producers + per-image spin-wait workers ----
// Blocks 0..7: workers. Blocks 8..2055: score (image-major, r7-verified body).
// Producer ordering: sc1 key stores -> __syncthreads (vmcnt drain) ->
// sc1 segcnt store -> s_waitcnt vmcnt(0) -> sc1 fetch_add done[b].
// Producers never wait -> deadlock-free. LDS ~79.7KB -> 2 blocks/CU, so
// score keeps 24 waves/CU; workers 0..6 hide under the HBM-bound phase.
__global__ __launch_bounds__(NTH) void k_mega(
    const float* __restrict__ cls, const float* __restrict__ regs,
    const float* __restrict__ anch, const int* __restrict__ isz,
    const int* __restrict__ iszo, const float* __restrict__ sthr_p,
    const float* __restrict__ nthr_p, u64* __restrict__ cseg,
    unsigned* __restrict__ segcnt, unsigned* __restrict__ done,
    float* __restrict__ out) {
#pragma clang fp contract(off)
  __shared__ __align__(16) char S[76800];
  __shared__ unsigned wsum[12];
  __shared__ unsigned segc[NSEG];
  __shared__ unsigned sofsL[NSEG + 1];
  __shared__ unsigned wcar[4];
  __shared__ int lcnt[NC];
  __shared__ int lofs[NC + 1];
  __shared__ unsigned scnt;

  int tid = threadIdx.x;
  int bid = blockIdx.x;
  int lane = tid & 63, wid = tid >> 6;

  if (bid >= NWORK) {
    // ---------------- score producer (r7-verified body) ----------------
    int sbid = bid - NWORK;
    int b = sbid >> 8, blk = sbid & 255;
    int t0 = blk * SA;
    float* lds = (float*)S;
    if (tid == 0) scnt = 0u;
    int acnt = NN - t0; if (acnt > SA) acnt = SA;
    const float4* src = (const float4*)(cls + ((size_t)b * NN + t0) * NC);
    float4* dst = (float4*)lds;
    int elems4 = acnt * NC / 4;
    for (int t = tid; t < elems4; t += NTH) dst[t] = src[t];
    __syncthreads();
    int a = tid >> 2, q = tid & 3;
    float best = -1e30f; int bc = 0;
    if (a < acnt) {
      for (int c = q; c < NC; c += 4) {
        float v = lds[a * NC + c];
        if (v > best) { best = v; bc = c; }
      }
      float ov; int oc;
      ov = __shfl_xor(best, 1); oc = __shfl_xor(bc, 1);
      if (ov > best || (ov == best && oc < bc)) { best = ov; bc = oc; }
      ov = __shfl_xor(best, 2); oc = __shfl_xor(bc, 2);
      if (ov > best || (ov == best && oc < bc)) { best = ov; bc = oc; }
    }
    bool valid = (q == 0) && (a < acnt) && (best >= *sthr_p);
    u64 key = 0ULL;
    if (valid) {
      unsigned idx = (unsigned)(t0 + a);
      key = ((u64)__float_as_uint(best) << 32) |
            ((u64)(0xFFFFu - idx) << 16) | (u64)(unsigned)bc;
    }
    __syncthreads();          // all lds reads finished; kbuf may overwrite
    u64* kbuf = (u64*)S;
    u64 m = __ballot(valid);
    if (m) {
      int leader = (int)__ffsll((unsigned long long)m) - 1;
      unsigned base = 0;
      if (lane == leader) base = atomicAdd(&scnt, (unsigned)__popcll(m));
      base = __shfl(base, leader);
      if (valid) {
        unsigned pos = base + (unsigned)__popcll(m & ((1ULL << lane) - 1ULL));
        kbuf[pos] = key;      // pos < 192 guaranteed
      }
    }
    __syncthreads();
    unsigned cnt = scnt;
    u64* dseg = cseg + ((size_t)b * NSEG + blk) * SA;
    for (unsigned t = tid; t < cnt; t += NTH) astore64(&dseg[t], kbuf[t]);
    __syncthreads();          // drains vmcnt: all sc1 key stores complete
    if (tid == 0) {
      astore32(&segcnt[b * NSEG + blk], cnt);
      asm volatile("s_waitcnt vmcnt(0)" ::: "memory");  // count before done
      __hip_atomic_fetch_add(&done[b], 1u, __ATOMIC_RELAXED,
                             __HIP_MEMORY_SCOPE_AGENT);
    }
    return;
  }

  // ---------------- worker (one block per image) ----------------
  int b = bid;
  u64* outk = (u64*)S;                      // [0, 55296)
  unsigned* hist = (unsigned*)(S + 55296);  // [55296, 76800): 5376 u32

  for (int i = tid; i < HISTN; i += NTH) hist[i] = 0u;
  if (tid == 0) {
    while (__hip_atomic_load(&done[b], __ATOMIC_RELAXED,
                             __HIP_MEMORY_SCOPE_AGENT) < NSEG)
      __builtin_amdgcn_s_sleep(2);
  }
  __syncthreads();

  if (tid < NSEG) {
    unsigned c = aload32(&segcnt[b * NSEG + tid]); if (c > SA) c = SA;
    segc[tid] = c;
  }
  __syncthreads();

  // exclusive scan of 256 segment counts (4 full waves + carry)
  unsigned vv = 0;
  if (tid < NSEG) {
    vv = segc[tid];
    for (int d = 1; d < 64; d <<= 1) {
      unsigned o = __shfl_up(vv, d);
      if (lane >= d) vv += o;
    }
    if (lane == 63) wcar[wid] = vv;
  }
  __syncthreads();
  if (tid < NSEG) {
    unsigned add = 0;
    for (int w = 0; w < wid; w++) add += wcar[w];
    sofsL[tid] = add + vv - segc[tid];
    if (tid == NSEG - 1) sofsL[NSEG] = add + vv;
  }
  __syncthreads();
  unsigned total = sofsL[NSEG]; if (total > CAP) total = CAP;

  // pass 1: histogram (keys read straight from global via sc1, no cand[])
  {
    int s = tid / 3, sub = tid - s * 3;
    unsigned c = segc[s], o = sofsL[s];
    const u64* srcp = cseg + ((size_t)b * NSEG + s) * SA;
    for (unsigned j = sub; j < c; j += 3) {
      if (o + j < CAP) {
        u64 key = aload64(&srcp[j]);
        unsigned bin = (0x3F800000u - (unsigned)(key >> 32) - 1u) >> 2;
        if (bin >= NB2) bin = NB2 - 1;
        atomicAdd(&hist[bin], 1u);
      }
    }
  }
  __syncthreads();

  // exclusive prefix scan: 7 bins/thread, wave scan + cross-wave scan
  int base7 = tid * 7;
  unsigned mysum = 0;
#pragma unroll
  for (int i = 0; i < 7; i++) mysum += hist[base7 + i];
  unsigned v = mysum;
  for (int d = 1; d < 64; d <<= 1) {
    unsigned o = __shfl_up(v, d);
    if (lane >= d) v += o;
  }
  if (lane == 63) wsum[wid] = v;
  __syncthreads();
  if (tid == 0) {
    unsigned acc = 0;
    for (int w2 = 0; w2 < 12; w2++) { unsigned c = wsum[w2]; wsum[w2] = acc; acc += c; }
  }
  __syncthreads();
  unsigned running = wsum[wid] + v - mysum;
#pragma unroll
  for (int i = 0; i < 7; i++) {
    unsigned c = hist[base7 + i];
    hist[base7 + i] = running;
    running += c;
  }
  __syncthreads();

  // pass 2: scatter into bin slots (re-read keys via sc1; any order within a
  // bin is fine -> tie-sort fully re-sorts each bin by full key)
  {
    int s = tid / 3, sub = tid - s * 3;
    unsigned c = segc[s], o = sofsL[s];
    const u64* srcp = cseg + ((size_t)b * NSEG + s) * SA;
    for (unsigned j = sub; j < c; j += 3) {
      if (o + j < CAP) {
        u64 key = aload64(&srcp[j]);
        unsigned bin = (0x3F800000u - (unsigned)(key >> 32) - 1u) >> 2;
        if (bin >= NB2) bin = NB2 - 1;
        unsigned pos = atomicAdd(&hist[bin], 1u);
        if (pos < CAP) outk[pos] = key;
      }
    }
  }
  __syncthreads();

  // insertion sort ties within each bin (full u64 key -> deterministic order)
  for (int bin = tid; bin < NB2; bin += NTH) {
    unsigned hi = hist[bin];
    unsigned lo = bin ? hist[bin - 1] : 0u;
    if (hi > CAP) hi = CAP;
    if (lo > CAP) lo = CAP;
    if (hi > lo + 1) {
      for (unsigned i2 = lo + 1; i2 < hi; i2++) {
        u64 kx = outk[i2];
        int j = (int)i2 - 1;
        while (j >= (int)lo && outk[j] < kx) { outk[j + 1] = outk[j]; j--; }
        outk[j + 1] = kx;
      }
    }
  }
  __syncthreads();

  // ---- phase B: decode top-n + per-class NMS over overlaid LDS ----
  // Overlay entirely within outk/hist dead zones: outk[<1000] (8000 B) is the
  // only region still read (decode); everything below starts at 8192.
  int n = (int)total; if (n > NK) n = NK;
  float4* bo = (float4*)(S + 8192);                     // [8192, 24192)
  unsigned short* llab = (unsigned short*)(S + 24192);  // [24192, 26192)
  unsigned short* sidx = (unsigned short*)(S + 26192);  // [26192, 28192)
  unsigned char* live = (unsigned char*)(S + 28192);    // [28192, 29192)
  u64* clsbits = (u64*)(S + 29200);                     // [29200, 40720) 90x16
  u64* nmsmask = (u64*)(S + 40720);                     // [40720, 63760) 90x32

  float H = (float)isz[b * 2 + 0];
  float W = (float)isz[b * 2 + 1];
  float scale = (float)iszo[b * 2 + 0] / H;
  float offmul = fmaxf(W, H) + 1.0f;
  for (int i = tid; i < NC * 16; i += NTH) clsbits[i] = 0ULL;
  for (int k = tid; k < n; k += NTH) {
    u64 key = outk[k];
    float sc = __uint_as_float((unsigned)(key >> 32));
    unsigned idx = 0xFFFFu - (unsigned)((key >> 16) & 0xFFFFull);
    int lab = (int)(key & 0xFFFFull);
    float raw[4];
    float4 rg = ((const float4*)regs)[(size_t)b * NN + idx];
    float4 an = ((const float4*)anch)[idx];
    decode_box(rg, an, W, H, raw);
    float off = (float)lab * offmul;
    bo[k] = make_float4(raw[0] + off, raw[1] + off, raw[2] + off, raw[3] + off);
    llab[k] = (unsigned short)lab;
    live[k] = 1;
    int g = b * NK + k;
    float* o5 = out + (size_t)g * 5;
    o5[0] = raw[0] * scale; o5[1] = raw[1] * scale;
    o5[2] = raw[2] * scale; o5[3] = raw[3] * scale;
    o5[4] = sc;
    out[(size_t)NB * NK * 5 + g] = (float)lab;
  }
  __syncthreads();

  // per-class membership bitmaps (k ascending == score descending)
  for (int k = tid; k < n; k += NTH)
    atomicOr(&clsbits[(int)llab[k] * 16 + (k >> 6)], 1ULL << (k & 63));
  __syncthreads();

  if (tid < NC) {
    unsigned cnt = 0;
#pragma unroll
    for (int w = 0; w < 16; w++) cnt += (unsigned)__popcll(clsbits[tid * 16 + w]);
    lcnt[tid] = (int)cnt;
  }
  __syncthreads();
  if (tid == 0) {
    int acc = 0;
    for (int c = 0; c < NC; c++) { lofs[c] = acc; acc += lcnt[c]; }
    lofs[NC] = acc;
  }
  __syncthreads();

  // deterministic rank placement: sidx buckets sorted ascending k, no sort
  for (int k = tid; k < n; k += NTH) {
    int lab = (int)llab[k];
    const u64* cb = &clsbits[lab * 16];
    int w0 = k >> 6;
    unsigned pos = 0;
    for (int w = 0; w < w0; w++) pos += (unsigned)__popcll(cb[w]);
    pos += (unsigned)__popcll(cb[w0] & ((1ULL << (k & 63)) - 1ULL));
    sidx[lofs[lab] + pos] = (unsigned short)k;
  }
  __syncthreads();

  // pair IoU, one suppression row per thread (fast path m<=32)
  float thr = *nthr_p;
  for (int p = tid; p < n; p += NTH) {
    int ki = (int)sidx[p];
    int lab = (int)llab[ki];
    int s = lofs[lab], e = lofs[lab + 1];
    int r = p - s;
    if (r < 32) {
      u64 mask = 0ULL;
      float4 Bb = bo[ki];
      float x0 = Bb.x, y0 = Bb.y, x1 = Bb.z, y1 = Bb.w;
      float ai = (x1 - x0) * (y1 - y0);
      int qe = e; if (qe > s + 32) qe = s + 32;
      for (int q = p + 1; q < qe; q++) {
        int kj = (int)sidx[q];
        float4 Cc = bo[kj];
        float aj = (Cc.z - Cc.x) * (Cc.w - Cc.y);
        float ltx = fmaxf(x0, Cc.x), lty = fmaxf(y0, Cc.y);
        float rbx = fminf(x1, Cc.z), rby = fminf(y1, Cc.w);
        float ww = fmaxf(rbx - ltx, 0.f), hh = fmaxf(rby - lty, 0.f);
        float inter = ww * hh;
        float den = ((ai + aj) - inter) + 1e-9f;
        float iou = inter / den;
        if (iou > thr) mask |= 1ULL << (q - s);
      }
      nmsmask[lab * 32 + r] = mask;
    }
  }
  __syncthreads();

  // per-class greedy chain: O(m) dependent LDS reads, register rem
  if (tid < NC) {
    int s = lofs[tid], e = lofs[tid + 1], m = e - s;
    if (m <= 32) {
      u64 rem = 0ULL;
      for (int r = 0; r < m; r++)
        if (!((rem >> r) & 1ULL)) rem |= nmsmask[tid * 32 + r];
      for (int r = 0; r < m; r++)
        live[(int)sidx[s + r]] = (unsigned char)(1ULL ^ ((rem >> r) & 1ULL));
    } else {
      // exact serial fallback (P(m>32) ~ 3e-8 per class)
      for (int r = 0; r < m; r++) live[(int)sidx[s + r]] = 1;
      for (int i = s; i < e; i++) {
        int ki = (int)sidx[i];
        if (!live[ki]) continue;
        float4 Bb = bo[ki];
        float x0 = Bb.x, y0 = Bb.y, x1 = Bb.z, y1 = Bb.w;
        float ai = (x1 - x0) * (y1 - y0);
        for (int j = i + 1; j < e; j++) {
          int kj = (int)sidx[j];
          if (!live[kj]) continue;
          float4 Cc = bo[kj];
          float aj = (Cc.z - Cc.x) * (Cc.w - Cc.y);
          float ltx = fmaxf(x0, Cc.x), lty = fmaxf(y0, Cc.y);
          float rbx = fminf(x1, Cc.z), rby = fminf(y1, Cc.w);
          float ww = fmaxf(rbx - ltx, 0.f), hh = fmaxf(rby - lty, 0.f);
          float inter = ww * hh;
          float den = ((ai + aj) - inter) + 1e-9f;
          float iou = inter / den;
          if (iou > thr) live[kj] = 0;
        }
      }
    }
  }
  __syncthreads();

  for (int k = tid; k < NK; k += NTH) {
    int g = b * NK + k;
    int keep = (k < n) ? (int)live[k] : 0;
    if (keep) {
      out[(size_t)NB * NK * 6 + g] = 1.0f;
    } else {
      float* o5 = out + (size_t)g * 5;
      o5[0] = 0.f; o5[1] = 0.f; o5[2] = 0.f; o5[3] = 0.f; o5[4] = 0.f;
      out[(size_t)NB * NK * 5 + g] = -1.0f;
      out[(size_t)NB * NK * 6 + g] = 0.0f;
    }
  }
}

extern "C" void kernel_launch(void* const* d_in, const int* in_sizes, int n_in,
                              void* d_out, int out_size, void* d_ws, size_t ws_size,
                              hipStream_t stream) {
  const float* cls = (const float*)d_in[0];
  const float* regs = (const float*)d_in[1];
  const float* anch = (const float*)d_in[2];
  const int* isz = (const int*)d_in[3];
  const int* iszo = (const int*)d_in[4];
  const float* sthr = (const float*)d_in[5];
  const float* nthr = (const float*)d_in[6];
  float* out = (float*)d_out;

  char* p = (char*)d_ws;
  auto alloc = [&](size_t bytes) {
    char* r = p;
    p += (bytes + 255) & ~(size_t)255;
    return r;
  };
  u64* cseg = (u64*)alloc((size_t)NB * NSEG * SA * 8);       // 3.15 MB
  unsigned* segcnt = (unsigned*)alloc((size_t)NB * NSEG * 4);
  unsigned* done = (unsigned*)alloc((size_t)NB * 4);

  hipMemsetAsync(done, 0, (size_t)NB * sizeof(unsigned), stream);
  hipLaunchKernelGGL(k_mega, dim3(NWORK + NB * NSEG), dim3(NTH), 0, stream,
                     cls, regs, anch, isz, iszo, sthr, nthr,
                     cseg, segcnt, done, out);
}

// Round 9
// 70.837 us; speedup vs baseline: 1.1902x; 1.1902x over previous
//
#include <hip/hip_runtime.h>
#include <stdint.h>

#define NB 8
#define NN 49104
#define NC 90
#define NK 1000
#define SA 192        // anchors per score block
#define NSEG 256      // score blocks (= key segments) per image
#define NTH 768       // threads per block (score: 4/anchor; worker: all phases)
#define CAP 6912      // worker candidate capacity (expected ~4224, 43 sigma)
#define NB2 4352      // 4-ULP-wide score bins
#define HISTN 5376    // 768*7 chunk-7 scan domain (bins >= NB2 stay zero)
#define NWORK 8
#define DSTRIDE 64    // done[] counter stride in u32 (256B): r8 lesson - 2048
                      // fetch_adds on ONE packed 32B line serialize ~45ns/op
                      // at the coherence point = ~92us gating the workers.

typedef unsigned long long u64;

// Agent-scope relaxed atomics: sc1 route (bypass non-coherent per-XCD L2).
// NO release/acquire anywhere -> no buffer_wbl2 (the r3 disaster).
__device__ __forceinline__ u64 aload64(const u64* p) {
  return __hip_atomic_load(p, __ATOMIC_RELAXED, __HIP_MEMORY_SCOPE_AGENT);
}
__device__ __forceinline__ void astore64(u64* p, u64 v) {
  __hip_atomic_store(p, v, __ATOMIC_RELAXED, __HIP_MEMORY_SCOPE_AGENT);
}
__device__ __forceinline__ unsigned aload32(const unsigned* p) {
  return __hip_atomic_load(p, __ATOMIC_RELAXED, __HIP_MEMORY_SCOPE_AGENT);
}
__device__ __forceinline__ void astore32(unsigned* p, unsigned v) {
  __hip_atomic_store(p, v, __ATOMIC_RELAXED, __HIP_MEMORY_SCOPE_AGENT);
}

__device__ __forceinline__ void decode_box(const float4 rg, const float4 an,
                                           float W, float H, float* out) {
#pragma clang fp contract(off)
  float l = an.x, t = an.y, r = an.z, bo = an.w;
  float wa = r - l, ha = bo - t;
  float cxa = l + wa * 0.5f, cya = t + ha * 0.5f;
  float cx = cxa + rg.x * wa;
  float cy = cya + rg.y * ha;
  float w = wa * expf(rg.z);
  float h = ha * expf(rg.w);
  float left = cx - w * 0.5f, top = cy - h * 0.5f;
  float right = left + w, botm = top + h;
  out[0] = fminf(fmaxf(left, 0.f), W - 1.f);
  out[1] = fminf(fmaxf(top, 0.f), H - 1.f);
  out[2] = fminf(fmaxf(right, 0.f), W - 1.f);
  out[3] = fminf(fmaxf(botm, 0.f), H - 1.f);
}

// ---- single mega-kernel: score producers + per-image spin-wait workers ----
// Blocks 0..7: workers. Blocks 8..2055: score (image-major, r7-verified body).
// Producer ordering: sc1 key stores -> __syncthreads (vmcnt drain) ->
// sc1 segcnt store -> s_waitcnt vmcnt(0) -> sc1 fetch_add done[b*DSTRIDE].
// Producers never wait -> deadlock-free. done counters on separate 256B
// lines -> per-line atomic serialization is 256 adds spread over the score
// phase (vs r8's 2048-on-one-line = 92us).
__global__ __launch_bounds__(NTH) void k_mega(
    const float* __restrict__ cls, const float* __restrict__ regs,
    const float* __restrict__ anch, const int* __restrict__ isz,
    const int* __restrict__ iszo, const float* __restrict__ sthr_p,
    const float* __restrict__ nthr_p, u64* __restrict__ cseg,
    unsigned* __restrict__ segcnt, unsigned* __restrict__ done,
    float* __restrict__ out) {
#pragma clang fp contract(off)
  __shared__ __align__(16) char S[76800];
  __shared__ unsigned wsum[12];
  __shared__ unsigned segc[NSEG];
  __shared__ unsigned sofsL[NSEG + 1];
  __shared__ unsigned wcar[4];
  __shared__ int lcnt[NC];
  __shared__ int lofs[NC + 1];
  __shared__ unsigned scnt;

  int tid = threadIdx.x;
  int bid = blockIdx.x;
  int lane = tid & 63, wid = tid >> 6;

  if (bid >= NWORK) {
    // ---------------- score producer (r7-verified body) ----------------
    int sbid = bid - NWORK;
    int b = sbid >> 8, blk = sbid & 255;
    int t0 = blk * SA;
    float* lds = (float*)S;
    if (tid == 0) scnt = 0u;
    int acnt = NN - t0; if (acnt > SA) acnt = SA;
    const float4* src = (const float4*)(cls + ((size_t)b * NN + t0) * NC);
    float4* dst = (float4*)lds;
    int elems4 = acnt * NC / 4;
    for (int t = tid; t < elems4; t += NTH) dst[t] = src[t];
    __syncthreads();
    int a = tid >> 2, q = tid & 3;
    float best = -1e30f; int bc = 0;
    if (a < acnt) {
      for (int c = q; c < NC; c += 4) {
        float v = lds[a * NC + c];
        if (v > best) { best = v; bc = c; }
      }
      float ov; int oc;
      ov = __shfl_xor(best, 1); oc = __shfl_xor(bc, 1);
      if (ov > best || (ov == best && oc < bc)) { best = ov; bc = oc; }
      ov = __shfl_xor(best, 2); oc = __shfl_xor(bc, 2);
      if (ov > best || (ov == best && oc < bc)) { best = ov; bc = oc; }
    }
    bool valid = (q == 0) && (a < acnt) && (best >= *sthr_p);
    u64 key = 0ULL;
    if (valid) {
      unsigned idx = (unsigned)(t0 + a);
      key = ((u64)__float_as_uint(best) << 32) |
            ((u64)(0xFFFFu - idx) << 16) | (u64)(unsigned)bc;
    }
    __syncthreads();          // all lds reads finished; kbuf may overwrite
    u64* kbuf = (u64*)S;
    u64 m = __ballot(valid);
    if (m) {
      int leader = (int)__ffsll((unsigned long long)m) - 1;
      unsigned base = 0;
      if (lane == leader) base = atomicAdd(&scnt, (unsigned)__popcll(m));
      base = __shfl(base, leader);
      if (valid) {
        unsigned pos = base + (unsigned)__popcll(m & ((1ULL << lane) - 1ULL));
        kbuf[pos] = key;      // pos < 192 guaranteed
      }
    }
    __syncthreads();
    unsigned cnt = scnt;
    u64* dseg = cseg + ((size_t)b * NSEG + blk) * SA;
    for (unsigned t = tid; t < cnt; t += NTH) astore64(&dseg[t], kbuf[t]);
    __syncthreads();          // drains vmcnt: all sc1 key stores complete
    if (tid == 0) {
      astore32(&segcnt[b * NSEG + blk], cnt);
      asm volatile("s_waitcnt vmcnt(0)" ::: "memory");  // count before done
      __hip_atomic_fetch_add(&done[b * DSTRIDE], 1u, __ATOMIC_RELAXED,
                             __HIP_MEMORY_SCOPE_AGENT);
    }
    return;
  }

  // ---------------- worker (one block per image) ----------------
  int b = bid;
  u64* outk = (u64*)S;                      // [0, 55296)
  unsigned* hist = (unsigned*)(S + 55296);  // [55296, 76800): 5376 u32

  for (int i = tid; i < HISTN; i += NTH) hist[i] = 0u;
  if (tid == 0) {
    while (__hip_atomic_load(&done[b * DSTRIDE], __ATOMIC_RELAXED,
                             __HIP_MEMORY_SCOPE_AGENT) < NSEG)
      __builtin_amdgcn_s_sleep(2);
  }
  __syncthreads();

  if (tid < NSEG) {
    unsigned c = aload32(&segcnt[b * NSEG + tid]); if (c > SA) c = SA;
    segc[tid] = c;
  }
  __syncthreads();

  // exclusive scan of 256 segment counts (4 full waves + carry)
  unsigned vv = 0;
  if (tid < NSEG) {
    vv = segc[tid];
    for (int d = 1; d < 64; d <<= 1) {
      unsigned o = __shfl_up(vv, d);
      if (lane >= d) vv += o;
    }
    if (lane == 63) wcar[wid] = vv;
  }
  __syncthreads();
  if (tid < NSEG) {
    unsigned add = 0;
    for (int w = 0; w < wid; w++) add += wcar[w];
    sofsL[tid] = add + vv - segc[tid];
    if (tid == NSEG - 1) sofsL[NSEG] = add + vv;
  }
  __syncthreads();
  unsigned total = sofsL[NSEG]; if (total > CAP) total = CAP;

  // pass 1: histogram (keys read straight from global via sc1, no cand[])
  {
    int s = tid / 3, sub = tid - s * 3;
    unsigned c = segc[s], o = sofsL[s];
    const u64* srcp = cseg + ((size_t)b * NSEG + s) * SA;
    for (unsigned j = sub; j < c; j += 3) {
      if (o + j < CAP) {
        u64 key = aload64(&srcp[j]);
        unsigned bin = (0x3F800000u - (unsigned)(key >> 32) - 1u) >> 2;
        if (bin >= NB2) bin = NB2 - 1;
        atomicAdd(&hist[bin], 1u);
      }
    }
  }
  __syncthreads();

  // exclusive prefix scan: 7 bins/thread, wave scan + cross-wave scan
  int base7 = tid * 7;
  unsigned mysum = 0;
#pragma unroll
  for (int i = 0; i < 7; i++) mysum += hist[base7 + i];
  unsigned v = mysum;
  for (int d = 1; d < 64; d <<= 1) {
    unsigned o = __shfl_up(v, d);
    if (lane >= d) v += o;
  }
  if (lane == 63) wsum[wid] = v;
  __syncthreads();
  if (tid == 0) {
    unsigned acc = 0;
    for (int w2 = 0; w2 < 12; w2++) { unsigned c = wsum[w2]; wsum[w2] = acc; acc += c; }
  }
  __syncthreads();
  unsigned running = wsum[wid] + v - mysum;
#pragma unroll
  for (int i = 0; i < 7; i++) {
    unsigned c = hist[base7 + i];
    hist[base7 + i] = running;
    running += c;
  }
  __syncthreads();

  // pass 2: scatter into bin slots (re-read keys via sc1; any order within a
  // bin is fine -> tie-sort fully re-sorts each bin by full key)
  {
    int s = tid / 3, sub = tid - s * 3;
    unsigned c = segc[s], o = sofsL[s];
    const u64* srcp = cseg + ((size_t)b * NSEG + s) * SA;
    for (unsigned j = sub; j < c; j += 3) {
      if (o + j < CAP) {
        u64 key = aload64(&srcp[j]);
        unsigned bin = (0x3F800000u - (unsigned)(key >> 32) - 1u) >> 2;
        if (bin >= NB2) bin = NB2 - 1;
        unsigned pos = atomicAdd(&hist[bin], 1u);
        if (pos < CAP) outk[pos] = key;
      }
    }
  }
  __syncthreads();

  // insertion sort ties within each bin (full u64 key -> deterministic order)
  for (int bin = tid; bin < NB2; bin += NTH) {
    unsigned hi = hist[bin];
    unsigned lo = bin ? hist[bin - 1] : 0u;
    if (hi > CAP) hi = CAP;
    if (lo > CAP) lo = CAP;
    if (hi > lo + 1) {
      for (unsigned i2 = lo + 1; i2 < hi; i2++) {
        u64 kx = outk[i2];
        int j = (int)i2 - 1;
        while (j >= (int)lo && outk[j] < kx) { outk[j + 1] = outk[j]; j--; }
        outk[j + 1] = kx;
      }
    }
  }
  __syncthreads();

  // ---- phase B: decode top-n + per-class NMS over overlaid LDS ----
  // Overlay entirely within outk/hist dead zones: outk[<1000] (8000 B) is the
  // only region still read (decode); everything below starts at 8192.
  int n = (int)total; if (n > NK) n = NK;
  float4* bo = (float4*)(S + 8192);                     // [8192, 24192)
  unsigned short* llab = (unsigned short*)(S + 24192);  // [24192, 26192)
  unsigned short* sidx = (unsigned short*)(S + 26192);  // [26192, 28192)
  unsigned char* live = (unsigned char*)(S + 28192);    // [28192, 29192)
  u64* clsbits = (u64*)(S + 29200);                     // [29200, 40720) 90x16
  u64* nmsmask = (u64*)(S + 40720);                     // [40720, 63760) 90x32

  float H = (float)isz[b * 2 + 0];
  float W = (float)isz[b * 2 + 1];
  float scale = (float)iszo[b * 2 + 0] / H;
  float offmul = fmaxf(W, H) + 1.0f;
  for (int i = tid; i < NC * 16; i += NTH) clsbits[i] = 0ULL;
  for (int k = tid; k < n; k += NTH) {
    u64 key = outk[k];
    float sc = __uint_as_float((unsigned)(key >> 32));
    unsigned idx = 0xFFFFu - (unsigned)((key >> 16) & 0xFFFFull);
    int lab = (int)(key & 0xFFFFull);
    float raw[4];
    float4 rg = ((const float4*)regs)[(size_t)b * NN + idx];
    float4 an = ((const float4*)anch)[idx];
    decode_box(rg, an, W, H, raw);
    float off = (float)lab * offmul;
    bo[k] = make_float4(raw[0] + off, raw[1] + off, raw[2] + off, raw[3] + off);
    llab[k] = (unsigned short)lab;
    live[k] = 1;
    int g = b * NK + k;
    float* o5 = out + (size_t)g * 5;
    o5[0] = raw[0] * scale; o5[1] = raw[1] * scale;
    o5[2] = raw[2] * scale; o5[3] = raw[3] * scale;
    o5[4] = sc;
    out[(size_t)NB * NK * 5 + g] = (float)lab;
  }
  __syncthreads();

  // per-class membership bitmaps (k ascending == score descending)
  for (int k = tid; k < n; k += NTH)
    atomicOr(&clsbits[(int)llab[k] * 16 + (k >> 6)], 1ULL << (k & 63));
  __syncthreads();

  if (tid < NC) {
    unsigned cnt = 0;
#pragma unroll
    for (int w = 0; w < 16; w++) cnt += (unsigned)__popcll(clsbits[tid * 16 + w]);
    lcnt[tid] = (int)cnt;
  }
  __syncthreads();
  if (tid == 0) {
    int acc = 0;
    for (int c = 0; c < NC; c++) { lofs[c] = acc; acc += lcnt[c]; }
    lofs[NC] = acc;
  }
  __syncthreads();

  // deterministic rank placement: sidx buckets sorted ascending k, no sort
  for (int k = tid; k < n; k += NTH) {
    int lab = (int)llab[k];
    const u64* cb = &clsbits[lab * 16];
    int w0 = k >> 6;
    unsigned pos = 0;
    for (int w = 0; w < w0; w++) pos += (unsigned)__popcll(cb[w]);
    pos += (unsigned)__popcll(cb[w0] & ((1ULL << (k & 63)) - 1ULL));
    sidx[lofs[lab] + pos] = (unsigned short)k;
  }
  __syncthreads();

  // pair IoU, one suppression row per thread (fast path m<=32)
  float thr = *nthr_p;
  for (int p = tid; p < n; p += NTH) {
    int ki = (int)sidx[p];
    int lab = (int)llab[ki];
    int s = lofs[lab], e = lofs[lab + 1];
    int r = p - s;
    if (r < 32) {
      u64 mask = 0ULL;
      float4 Bb = bo[ki];
      float x0 = Bb.x, y0 = Bb.y, x1 = Bb.z, y1 = Bb.w;
      float ai = (x1 - x0) * (y1 - y0);
      int qe = e; if (qe > s + 32) qe = s + 32;
      for (int q = p + 1; q < qe; q++) {
        int kj = (int)sidx[q];
        float4 Cc = bo[kj];
        float aj = (Cc.z - Cc.x) * (Cc.w - Cc.y);
        float ltx = fmaxf(x0, Cc.x), lty = fmaxf(y0, Cc.y);
        float rbx = fminf(x1, Cc.z), rby = fminf(y1, Cc.w);
        float ww = fmaxf(rbx - ltx, 0.f), hh = fmaxf(rby - lty, 0.f);
        float inter = ww * hh;
        float den = ((ai + aj) - inter) + 1e-9f;
        float iou = inter / den;
        if (iou > thr) mask |= 1ULL << (q - s);
      }
      nmsmask[lab * 32 + r] = mask;
    }
  }
  __syncthreads();

  // per-class greedy chain: O(m) dependent LDS reads, register rem
  if (tid < NC) {
    int s = lofs[tid], e = lofs[tid + 1], m = e - s;
    if (m <= 32) {
      u64 rem = 0ULL;
      for (int r = 0; r < m; r++)
        if (!((rem >> r) & 1ULL)) rem |= nmsmask[tid * 32 + r];
      for (int r = 0; r < m; r++)
        live[(int)sidx[s + r]] = (unsigned char)(1ULL ^ ((rem >> r) & 1ULL));
    } else {
      // exact serial fallback (P(m>32) ~ 3e-8 per class)
      for (int r = 0; r < m; r++) live[(int)sidx[s + r]] = 1;
      for (int i = s; i < e; i++) {
        int ki = (int)sidx[i];
        if (!live[ki]) continue;
        float4 Bb = bo[ki];
        float x0 = Bb.x, y0 = Bb.y, x1 = Bb.z, y1 = Bb.w;
        float ai = (x1 - x0) * (y1 - y0);
        for (int j = i + 1; j < e; j++) {
          int kj = (int)sidx[j];
          if (!live[kj]) continue;
          float4 Cc = bo[kj];
          float aj = (Cc.z - Cc.x) * (Cc.w - Cc.y);
          float ltx = fmaxf(x0, Cc.x), lty = fmaxf(y0, Cc.y);
          float rbx = fminf(x1, Cc.z), rby = fminf(y1, Cc.w);
          float ww = fmaxf(rbx - ltx, 0.f), hh = fmaxf(rby - lty, 0.f);
          float inter = ww * hh;
          float den = ((ai + aj) - inter) + 1e-9f;
          float iou = inter / den;
          if (iou > thr) live[kj] = 0;
        }
      }
    }
  }
  __syncthreads();

  for (int k = tid; k < NK; k += NTH) {
    int g = b * NK + k;
    int keep = (k < n) ? (int)live[k] : 0;
    if (keep) {
      out[(size_t)NB * NK * 6 + g] = 1.0f;
    } else {
      float* o5 = out + (size_t)g * 5;
      o5[0] = 0.f; o5[1] = 0.f; o5[2] = 0.f; o5[3] = 0.f; o5[4] = 0.f;
      out[(size_t)NB * NK * 5 + g] = -1.0f;
      out[(size_t)NB * NK * 6 + g] = 0.0f;
    }
  }
}

extern "C" void kernel_launch(void* const* d_in, const int* in_sizes, int n_in,
                              void* d_out, int out_size, void* d_ws, size_t ws_size,
                              hipStream_t stream) {
  const float* cls = (const float*)d_in[0];
  const float* regs = (const float*)d_in[1];
  const float* anch = (const float*)d_in[2];
  const int* isz = (const int*)d_in[3];
  const int* iszo = (const int*)d_in[4];
  const float* sthr = (const float*)d_in[5];
  const float* nthr = (const float*)d_in[6];
  float* out = (float*)d_out;

  char* p = (char*)d_ws;
  auto alloc = [&](size_t bytes) {
    char* r = p;
    p += (bytes + 255) & ~(size_t)255;
    return r;
  };
  u64* cseg = (u64*)alloc((size_t)NB * NSEG * SA * 8);       // 3.15 MB
  unsigned* segcnt = (unsigned*)alloc((size_t)NB * NSEG * 4);
  unsigned* done = (unsigned*)alloc((size_t)NB * DSTRIDE * 4); // 256B/counter

  hipMemsetAsync(done, 0, (size_t)NB * DSTRIDE * sizeof(unsigned), stream);
  hipLaunchKernelGGL(k_mega, dim3(NWORK + NB * NSEG), dim3(NTH), 0, stream,
                     cls, regs, anch, isz, iszo, sthr, nthr,
                     cseg, segcnt, done, out);
}

// Round 11
// 52.684 us; speedup vs baseline: 1.6003x; 1.3446x over previous
//
#include <hip/hip_runtime.h>
#include <stdint.h>

#define NB 8
#define NN 49104
#define NC 90
#define NK 1000
#define SA 192        // anchors per score block
#define NSEG 256      // score blocks (= key segments) per image; NSEG*SA=49152
#define CAP2 8192     // candidate capacity in worker LDS
#define NB2 4352      // 4-ULP-wide score bins
#define NB2P 5120     // 1024*5 for chunk-5 prefix scan

typedef unsigned long long u64;
typedef float nfloat4 __attribute__((ext_vector_type(4)));  // native vec for
// __builtin_nontemporal_load (HIP_vector_type float4 is rejected, r10)

// ---- fused score + in-block compaction (r7-verified) ----
// key = (score_bits << 32) | ((0xFFFF - idx) << 16) | label
// Ballot-compact through LDS (1-link chain, LDS atomics only), burst-write
// to a private fixed-stride global segment + exact count.
__global__ __launch_bounds__(768) void k_score(const float* __restrict__ cls,
                                               const float* __restrict__ thr_p,
                                               u64* __restrict__ cseg,
                                               unsigned* __restrict__ segcnt) {
  __shared__ __align__(16) float lds[SA * NC];   // 69120 B; kbuf overlays later
  __shared__ unsigned scnt;
  int b = blockIdx.y;
  int blk = blockIdx.x;
  int t0 = blk * SA;
  int tid = threadIdx.x;
  int lane = tid & 63;
  if (tid == 0) scnt = 0u;
  int acnt = NN - t0; if (acnt > SA) acnt = SA;
  const nfloat4* src = (const nfloat4*)(cls + ((size_t)b * NN + t0) * NC);
  nfloat4* dst = (nfloat4*)lds;
  int elems4 = acnt * NC / 4;
  // cls is read exactly once -> nontemporal streaming loads (no L2 reuse)
  for (int t = tid; t < elems4; t += 768)
    dst[t] = __builtin_nontemporal_load(&src[t]);
  __syncthreads();
  int a = tid >> 2, q = tid & 3;
  float best = -1e30f; int bc = 0;
  if (a < acnt) {
    for (int c = q; c < NC; c += 4) {
      float v = lds[a * NC + c];
      if (v > best) { best = v; bc = c; }
    }
    float ov; int oc;
    ov = __shfl_xor(best, 1); oc = __shfl_xor(bc, 1);
    if (ov > best || (ov == best && oc < bc)) { best = ov; bc = oc; }
    ov = __shfl_xor(best, 2); oc = __shfl_xor(bc, 2);
    if (ov > best || (ov == best && oc < bc)) { best = ov; bc = oc; }
  }
  bool valid = (q == 0) && (a < acnt) && (best >= *thr_p);
  u64 key = 0ULL;
  if (valid) {
    unsigned idx = (unsigned)(t0 + a);
    key = ((u64)__float_as_uint(best) << 32) |
          ((u64)(0xFFFFu - idx) << 16) | (u64)(unsigned)bc;
  }
  __syncthreads();          // all lds reads finished; kbuf may overwrite
  u64* kbuf = (u64*)lds;
  u64 m = __ballot(valid);
  if (m) {
    int leader = (int)__ffsll((unsigned long long)m) - 1;
    unsigned base = 0;
    if (lane == leader) base = atomicAdd(&scnt, (unsigned)__popcll(m));
    base = __shfl(base, leader);
    if (valid) {
      unsigned pos = base + (unsigned)__popcll(m & ((1ULL << lane) - 1ULL));
      kbuf[pos] = key;      // pos < 192 guaranteed (<=192 owners/block)
    }
  }
  __syncthreads();
  unsigned cnt = scnt;
  u64* dseg = cseg + ((size_t)b * NSEG + blk) * SA;
  for (unsigned t = tid; t < cnt; t += 768) dseg[t] = kbuf[t];
  if (tid == 0) segcnt[b * NSEG + blk] = cnt;
}

__device__ __forceinline__ void decode_box(const float4 rg, const float4 an,
                                           float W, float H, float* out) {
#pragma clang fp contract(off)
  float l = an.x, t = an.y, r = an.z, bo = an.w;
  float wa = r - l, ha = bo - t;
  float cxa = l + wa * 0.5f, cya = t + ha * 0.5f;
  float cx = cxa + rg.x * wa;
  float cy = cya + rg.y * ha;
  float w = wa * expf(rg.z);
  float h = ha * expf(rg.w);
  float left = cx - w * 0.5f, top = cy - h * 0.5f;
  float right = left + w, botm = top + h;
  out[0] = fminf(fmaxf(left, 0.f), W - 1.f);
  out[1] = fminf(fmaxf(top, 0.f), H - 1.f);
  out[2] = fminf(fmaxf(right, 0.f), W - 1.f);
  out[3] = fminf(fmaxf(botm, 0.f), H - 1.f);
}

// ---- fused worker (r7-verified): segmented gather + counting sort +
//      tie sort + decode + per-class parallel NMS ----
__global__ __launch_bounds__(1024) void k_worker(
    const u64* __restrict__ cseg, const unsigned* __restrict__ segcnt,
    const float* __restrict__ regs, const float* __restrict__ anch,
    const int* __restrict__ isz, const int* __restrict__ iszo,
    const float* __restrict__ nthr_p, float* __restrict__ out) {
#pragma clang fp contract(off)
  __shared__ __align__(16) char S[151552];
  __shared__ unsigned wsum[16];
  __shared__ unsigned segc[NSEG];
  __shared__ unsigned sofsL[NSEG + 1];
  __shared__ unsigned wcar[4];
  __shared__ int lcnt[NC];
  __shared__ int lofs[NC + 1];

  u64* cand = (u64*)S;                       // [0, 65536)
  u64* outk = (u64*)(S + 65536);             // [65536, 131072)
  unsigned* hist = (unsigned*)(S + 131072);  // [131072, 151552)

  int tid = threadIdx.x;
  int lane = tid & 63, wid = tid >> 6;
  int b = blockIdx.x;

  for (int i = tid; i < NB2P; i += 1024) hist[i] = 0u;
  if (tid < NSEG) {
    unsigned c = segcnt[b * NSEG + tid]; if (c > SA) c = SA;
    segc[tid] = c;
  }
  __syncthreads();

  // exclusive scan of 256 segment counts (4 full waves + carry)
  unsigned vv = 0;
  if (tid < NSEG) {
    vv = segc[tid];
    for (int d = 1; d < 64; d <<= 1) {
      unsigned o = __shfl_up(vv, d);
      if (lane >= d) vv += o;
    }
    if (lane == 63) wcar[wid] = vv;
  }
  __syncthreads();
  if (tid < NSEG) {
    unsigned add = 0;
    for (int w = 0; w < wid; w++) add += wcar[w];
    sofsL[tid] = add + vv - segc[tid];
    if (tid == NSEG - 1) sofsL[NSEG] = add + vv;
  }
  __syncthreads();
  unsigned total = sofsL[NSEG]; if (total > CAP2) total = CAP2;

  // gather segments into cand + fused histogram (4 threads per segment)
  {
    int s = tid >> 2, sub = tid & 3;
    unsigned c = segc[s], o = sofsL[s];
    const u64* srcp = cseg + ((size_t)b * NSEG + s) * SA;
    for (unsigned j = sub; j < c; j += 4) {
      u64 key = srcp[j];
      unsigned pos = o + j;
      if (pos < CAP2) {
        cand[pos] = key;
        unsigned bin = (0x3F800000u - (unsigned)(key >> 32) - 1u) >> 2;
        if (bin >= NB2) bin = NB2 - 1;
        atomicAdd(&hist[bin], 1u);
      }
    }
  }
  __syncthreads();

  // exclusive prefix scan: 5 bins/thread, wave scan + cross-wave scan
  int base5 = tid * 5;
  unsigned mysum = 0;
#pragma unroll
  for (int i = 0; i < 5; i++) mysum += hist[base5 + i];
  unsigned v = mysum;
  for (int d = 1; d < 64; d <<= 1) {
    unsigned o = __shfl_up(v, d);
    if (lane >= d) v += o;
  }
  if (lane == 63) wsum[wid] = v;
  __syncthreads();
  if (tid == 0) {
    unsigned acc = 0;
    for (int w2 = 0; w2 < 16; w2++) { unsigned c = wsum[w2]; wsum[w2] = acc; acc += c; }
  }
  __syncthreads();
  unsigned running = wsum[wid] + v - mysum;
#pragma unroll
  for (int i = 0; i < 5; i++) {
    unsigned c = hist[base5 + i];
    hist[base5 + i] = running;
    running += c;
  }
  __syncthreads();

  // scatter into bin slots
  for (unsigned p = tid; p < total; p += 1024) {
    u64 key = cand[p];
    unsigned bin = (0x3F800000u - (unsigned)(key >> 32) - 1u) >> 2;
    if (bin >= NB2) bin = NB2 - 1;
    unsigned pos = atomicAdd(&hist[bin], 1u);
    if (pos < CAP2) outk[pos] = key;
  }
  __syncthreads();

  // insertion sort ties within each bin (full u64 key -> deterministic order).
  // outk[k] for k >= NK is never read downstream (decode stops at n <= NK),
  // so bins starting at lo >= NK are skipped entirely (~75% of work).
  for (int bin = tid; bin < NB2; bin += 1024) {
    unsigned hi = hist[bin];
    unsigned lo = bin ? hist[bin - 1] : 0u;
    if (lo >= NK) continue;          // bin cannot affect top-NK output
    if (hi > CAP2) hi = CAP2;
    if (lo > CAP2) lo = CAP2;
    if (hi > lo + 1) {
      for (unsigned i2 = lo + 1; i2 < hi; i2++) {
        u64 kx = outk[i2];
        int j = (int)i2 - 1;
        while (j >= (int)lo && outk[j] < kx) { outk[j + 1] = outk[j]; j--; }
        outk[j + 1] = kx;
      }
    }
  }
  __syncthreads();

  // ---- phase B: decode top-n + per-class NMS over overlaid LDS ----
  int n = (int)total; if (n > NK) n = NK;
  float4* bo = (float4*)S;                              // [0, 16000)
  unsigned short* llab = (unsigned short*)(S + 16000);  // [16000, 18000)
  unsigned short* sidx = (unsigned short*)(S + 18000);  // [18000, 20000)
  unsigned char* live = (unsigned char*)(S + 20000);    // [20000, 21000)
  u64* clsbits = (u64*)(S + 21008);                     // [21008, 32528) 90x16
  u64* nmsmask = (u64*)(S + 32536);                     // [32536, 78616) 90x64
  // clsbits/bo/llab/sidx/live sit in dead cand[]; nmsmask additionally
  // overlays outk[] but is only written AFTER decode consumed outk.

  float H = (float)isz[b * 2 + 0];
  float W = (float)isz[b * 2 + 1];
  float scale = (float)iszo[b * 2 + 0] / H;
  float offmul = fmaxf(W, H) + 1.0f;
  for (int i = tid; i < NC * 16; i += 1024) clsbits[i] = 0ULL;
  for (int k = tid; k < n; k += 1024) {
    u64 key = outk[k];
    float sc = __uint_as_float((unsigned)(key >> 32));
    unsigned idx = 0xFFFFu - (unsigned)((key >> 16) & 0xFFFFull);
    int lab = (int)(key & 0xFFFFull);
    float raw[4];
    float4 rg = ((const float4*)regs)[(size_t)b * NN + idx];
    float4 an = ((const float4*)anch)[idx];
    decode_box(rg, an, W, H, raw);
    float off = (float)lab * offmul;
    bo[k] = make_float4(raw[0] + off, raw[1] + off, raw[2] + off, raw[3] + off);
    llab[k] = (unsigned short)lab;
    live[k] = 1;
    int g = b * NK + k;
    float* o5 = out + (size_t)g * 5;
    o5[0] = raw[0] * scale; o5[1] = raw[1] * scale;
    o5[2] = raw[2] * scale; o5[3] = raw[3] * scale;
    o5[4] = sc;
    out[(size_t)NB * NK * 5 + g] = (float)lab;
  }
  __syncthreads();  // outk fully consumed; clsbits zeroed

  // per-class membership bitmaps (k ascending == score descending)
  for (int k = tid; k < n; k += 1024)
    atomicOr(&clsbits[(int)llab[k] * 16 + (k >> 6)], 1ULL << (k & 63));
  __syncthreads();

  if (tid < NC) {
    unsigned cnt = 0;
#pragma unroll
    for (int w = 0; w < 16; w++) cnt += (unsigned)__popcll(clsbits[tid * 16 + w]);
    lcnt[tid] = (int)cnt;
  }
  __syncthreads();
  if (tid == 0) {
    int acc = 0;
    for (int c = 0; c < NC; c++) { lofs[c] = acc; acc += lcnt[c]; }
    lofs[NC] = acc;
  }
  __syncthreads();

  // deterministic rank placement: sidx buckets sorted ascending k, no sort
  for (int k = tid; k < n; k += 1024) {
    int lab = (int)llab[k];
    const u64* cb = &clsbits[lab * 16];
    int w0 = k >> 6;
    unsigned pos = 0;
    for (int w = 0; w < w0; w++) pos += (unsigned)__popcll(cb[w]);
    pos += (unsigned)__popcll(cb[w0] & ((1ULL << (k & 63)) - 1ULL));
    sidx[lofs[lab] + pos] = (unsigned short)k;
  }
  __syncthreads();

  // pair IoU, one suppression row per thread (1024-wide parallel).
  // sidx[p] < sidx[q] for p<q in a bucket -> verbatim i<j operand order.
  float thr = *nthr_p;
  for (int p = tid; p < n; p += 1024) {
    int ki = (int)sidx[p];
    int lab = (int)llab[ki];
    int s = lofs[lab], e = lofs[lab + 1];
    int r = p - s;
    if (r < 64) {
      u64 mask = 0ULL;
      float4 Bb = bo[ki];
      float x0 = Bb.x, y0 = Bb.y, x1 = Bb.z, y1 = Bb.w;
      float ai = (x1 - x0) * (y1 - y0);
      int qe = e; if (qe > s + 64) qe = s + 64;
      for (int q = p + 1; q < qe; q++) {
        int kj = (int)sidx[q];
        float4 Cc = bo[kj];
        float aj = (Cc.z - Cc.x) * (Cc.w - Cc.y);
        float ltx = fmaxf(x0, Cc.x), lty = fmaxf(y0, Cc.y);
        float rbx = fminf(x1, Cc.z), rby = fminf(y1, Cc.w);
        float ww = fmaxf(rbx - ltx, 0.f), hh = fmaxf(rby - lty, 0.f);
        float inter = ww * hh;
        float den = ((ai + aj) - inter) + 1e-9f;
        float iou = inter / den;
        if (iou > thr) mask |= 1ULL << (q - s);
      }
      nmsmask[lab * 64 + r] = mask;   // row owned by exactly this thread
    }
  }
  __syncthreads();

  // per-class greedy chain: O(m) dependent LDS reads, register rem
  if (tid < NC) {
    int s = lofs[tid], e = lofs[tid + 1], m = e - s;
    if (m <= 64) {
      u64 rem = 0ULL;
      for (int r = 0; r < m; r++)
        if (!((rem >> r) & 1ULL)) rem |= nmsmask[tid * 64 + r];
      for (int r = 0; r < m; r++)
        live[(int)sidx[s + r]] = (unsigned char)(1ULL ^ ((rem >> r) & 1ULL));
    } else {
      // exact fallback (bucket > 64: statistically unreachable here)
      for (int r = 0; r < m; r++) live[(int)sidx[s + r]] = 1;
      for (int i = s; i < e; i++) {
        int ki = (int)sidx[i];
        if (!live[ki]) continue;
        float4 Bb = bo[ki];
        float x0 = Bb.x, y0 = Bb.y, x1 = Bb.z, y1 = Bb.w;
        float ai = (x1 - x0) * (y1 - y0);
        for (int j = i + 1; j < e; j++) {
          int kj = (int)sidx[j];
          if (!live[kj]) continue;
          float4 Cc = bo[kj];
          float aj = (Cc.z - Cc.x) * (Cc.w - Cc.y);
          float ltx = fmaxf(x0, Cc.x), lty = fmaxf(y0, Cc.y);
          float rbx = fminf(x1, Cc.z), rby = fminf(y1, Cc.w);
          float ww = fmaxf(rbx - ltx, 0.f), hh = fmaxf(rby - lty, 0.f);
          float inter = ww * hh;
          float den = ((ai + aj) - inter) + 1e-9f;
          float iou = inter / den;
          if (iou > thr) live[kj] = 0;
        }
      }
    }
  }
  __syncthreads();

  for (int k = tid; k < NK; k += 1024) {
    int g = b * NK + k;
    int keep = (k < n) ? (int)live[k] : 0;
    if (keep) {
      out[(size_t)NB * NK * 6 + g] = 1.0f;
    } else {
      float* o5 = out + (size_t)g * 5;
      o5[0] = 0.f; o5[1] = 0.f; o5[2] = 0.f; o5[3] = 0.f; o5[4] = 0.f;
      out[(size_t)NB * NK * 5 + g] = -1.0f;
      out[(size_t)NB * NK * 6 + g] = 0.0f;
    }
  }
}

extern "C" void kernel_launch(void* const* d_in, const int* in_sizes, int n_in,
                              void* d_out, int out_size, void* d_ws, size_t ws_size,
                              hipStream_t stream) {
  const float* cls = (const float*)d_in[0];
  const float* regs = (const float*)d_in[1];
  const float* anch = (const float*)d_in[2];
  const int* isz = (const int*)d_in[3];
  const int* iszo = (const int*)d_in[4];
  const float* sthr = (const float*)d_in[5];
  const float* nthr = (const float*)d_in[6];
  float* out = (float*)d_out;

  char* p = (char*)d_ws;
  auto alloc = [&](size_t bytes) {
    char* r = p;
    p += (bytes + 255) & ~(size_t)255;
    return r;
  };
  u64* cseg = (u64*)alloc((size_t)NB * NSEG * SA * 8);       // 3.15 MB
  unsigned* segcnt = (unsigned*)alloc((size_t)NB * NSEG * 4);

  hipLaunchKernelGGL(k_score, dim3(NSEG, NB), dim3(768), 0, stream,
                     cls, sthr, cseg, segcnt);
  hipLaunchKernelGGL(k_worker, dim3(NB), dim3(1024), 0, stream,
                     cseg, segcnt, regs, anch, isz, iszo, nthr, out);
}

// Round 12
// 52.352 us; speedup vs baseline: 1.6105x; 1.0064x over previous
//
#include <hip/hip_runtime.h>
#include <stdint.h>

#define NB 8
#define NN 49104
#define NC 90
#define NK 1000
#define SA 192        // anchors per score block
#define NSEG 256      // score blocks (= key segments) per image; NSEG*SA=49152
#define CAP2 8192     // candidate capacity in worker LDS
#define NB2 4352      // 4-ULP-wide score bins
#define NB2P 5120     // 1024*5 for chunk-5 prefix scan

typedef unsigned long long u64;
typedef float nfloat4 __attribute__((ext_vector_type(4)));  // native vec for
// __builtin_nontemporal_load (HIP_vector_type float4 is rejected, r10)

// ---- fused score + in-block compaction (r7/r11-verified) ----
// key = (score_bits << 32) | ((0xFFFF - idx) << 16) | label
__global__ __launch_bounds__(768) void k_score(const float* __restrict__ cls,
                                               const float* __restrict__ thr_p,
                                               u64* __restrict__ cseg,
                                               unsigned* __restrict__ segcnt) {
  __shared__ __align__(16) float lds[SA * NC];   // 69120 B; kbuf overlays later
  __shared__ unsigned scnt;
  int b = blockIdx.y;
  int blk = blockIdx.x;
  int t0 = blk * SA;
  int tid = threadIdx.x;
  int lane = tid & 63;
  if (tid == 0) scnt = 0u;
  int acnt = NN - t0; if (acnt > SA) acnt = SA;
  const nfloat4* src = (const nfloat4*)(cls + ((size_t)b * NN + t0) * NC);
  nfloat4* dst = (nfloat4*)lds;
  int elems4 = acnt * NC / 4;
  // cls is read exactly once -> nontemporal streaming loads (no L2 reuse)
  for (int t = tid; t < elems4; t += 768)
    dst[t] = __builtin_nontemporal_load(&src[t]);
  __syncthreads();
  int a = tid >> 2, q = tid & 3;
  float best = -1e30f; int bc = 0;
  if (a < acnt) {
    for (int c = q; c < NC; c += 4) {
      float v = lds[a * NC + c];
      if (v > best) { best = v; bc = c; }
    }
    float ov; int oc;
    ov = __shfl_xor(best, 1); oc = __shfl_xor(bc, 1);
    if (ov > best || (ov == best && oc < bc)) { best = ov; bc = oc; }
    ov = __shfl_xor(best, 2); oc = __shfl_xor(bc, 2);
    if (ov > best || (ov == best && oc < bc)) { best = ov; bc = oc; }
  }
  bool valid = (q == 0) && (a < acnt) && (best >= *thr_p);
  u64 key = 0ULL;
  if (valid) {
    unsigned idx = (unsigned)(t0 + a);
    key = ((u64)__float_as_uint(best) << 32) |
          ((u64)(0xFFFFu - idx) << 16) | (u64)(unsigned)bc;
  }
  __syncthreads();          // all lds reads finished; kbuf may overwrite
  u64* kbuf = (u64*)lds;
  u64 m = __ballot(valid);
  if (m) {
    int leader = (int)__ffsll((unsigned long long)m) - 1;
    unsigned base = 0;
    if (lane == leader) base = atomicAdd(&scnt, (unsigned)__popcll(m));
    base = __shfl(base, leader);
    if (valid) {
      unsigned pos = base + (unsigned)__popcll(m & ((1ULL << lane) - 1ULL));
      kbuf[pos] = key;      // pos < 192 guaranteed (<=192 owners/block)
    }
  }
  __syncthreads();
  unsigned cnt = scnt;
  u64* dseg = cseg + ((size_t)b * NSEG + blk) * SA;
  for (unsigned t = tid; t < cnt; t += 768) dseg[t] = kbuf[t];
  if (tid == 0) segcnt[b * NSEG + blk] = cnt;
}

__device__ __forceinline__ void decode_box(const float4 rg, const float4 an,
                                           float W, float H, float* out) {
#pragma clang fp contract(off)
  float l = an.x, t = an.y, r = an.z, bo = an.w;
  float wa = r - l, ha = bo - t;
  float cxa = l + wa * 0.5f, cya = t + ha * 0.5f;
  float cx = cxa + rg.x * wa;
  float cy = cya + rg.y * ha;
  float w = wa * expf(rg.z);
  float h = ha * expf(rg.w);
  float left = cx - w * 0.5f, top = cy - h * 0.5f;
  float right = left + w, botm = top + h;
  out[0] = fminf(fmaxf(left, 0.f), W - 1.f);
  out[1] = fminf(fmaxf(top, 0.f), H - 1.f);
  out[2] = fminf(fmaxf(right, 0.f), W - 1.f);
  out[3] = fminf(fmaxf(botm, 0.f), H - 1.f);
}

// ---- fused worker (r11-verified): segmented gather + counting sort +
//      tie sort + decode + per-class parallel NMS.
// r12 change: the two serial tid==0 prefix loops (90-class lofs, 16-wave
// wsum) become single-wave shfl scans (exact integer prefix, bit-identical).
__global__ __launch_bounds__(1024) void k_worker(
    const u64* __restrict__ cseg, const unsigned* __restrict__ segcnt,
    const float* __restrict__ regs, const float* __restrict__ anch,
    const int* __restrict__ isz, const int* __restrict__ iszo,
    const float* __restrict__ nthr_p, float* __restrict__ out) {
#pragma clang fp contract(off)
  __shared__ __align__(16) char S[151552];
  __shared__ unsigned wsum[16];
  __shared__ unsigned segc[NSEG];
  __shared__ unsigned sofsL[NSEG + 1];
  __shared__ unsigned wcar[4];
  __shared__ int lcnt[NC];
  __shared__ int lofs[NC + 1];

  u64* cand = (u64*)S;                       // [0, 65536)
  u64* outk = (u64*)(S + 65536);             // [65536, 131072)
  unsigned* hist = (unsigned*)(S + 131072);  // [131072, 151552)

  int tid = threadIdx.x;
  int lane = tid & 63, wid = tid >> 6;
  int b = blockIdx.x;

  for (int i = tid; i < NB2P; i += 1024) hist[i] = 0u;
  if (tid < NSEG) {
    unsigned c = segcnt[b * NSEG + tid]; if (c > SA) c = SA;
    segc[tid] = c;
  }
  __syncthreads();

  // exclusive scan of 256 segment counts (4 full waves + carry)
  unsigned vv = 0;
  if (tid < NSEG) {
    vv = segc[tid];
    for (int d = 1; d < 64; d <<= 1) {
      unsigned o = __shfl_up(vv, d);
      if (lane >= d) vv += o;
    }
    if (lane == 63) wcar[wid] = vv;
  }
  __syncthreads();
  if (tid < NSEG) {
    unsigned add = 0;
    for (int w = 0; w < wid; w++) add += wcar[w];
    sofsL[tid] = add + vv - segc[tid];
    if (tid == NSEG - 1) sofsL[NSEG] = add + vv;
  }
  __syncthreads();
  unsigned total = sofsL[NSEG]; if (total > CAP2) total = CAP2;

  // gather segments into cand + fused histogram (4 threads per segment)
  {
    int s = tid >> 2, sub = tid & 3;
    unsigned c = segc[s], o = sofsL[s];
    const u64* srcp = cseg + ((size_t)b * NSEG + s) * SA;
    for (unsigned j = sub; j < c; j += 4) {
      u64 key = srcp[j];
      unsigned pos = o + j;
      if (pos < CAP2) {
        cand[pos] = key;
        unsigned bin = (0x3F800000u - (unsigned)(key >> 32) - 1u) >> 2;
        if (bin >= NB2) bin = NB2 - 1;
        atomicAdd(&hist[bin], 1u);
      }
    }
  }
  __syncthreads();

  // exclusive prefix scan: 5 bins/thread, wave scan + cross-wave scan
  int base5 = tid * 5;
  unsigned mysum = 0;
#pragma unroll
  for (int i = 0; i < 5; i++) mysum += hist[base5 + i];
  unsigned v = mysum;
  for (int d = 1; d < 64; d <<= 1) {
    unsigned o = __shfl_up(v, d);
    if (lane >= d) v += o;
  }
  if (lane == 63) wsum[wid] = v;
  __syncthreads();
  // parallel exclusive scan of the 16 wave totals (was serial tid==0 loop)
  if (tid < 64) {
    unsigned c16 = (tid < 16) ? wsum[tid] : 0u;
    unsigned vs = c16;
    for (int d = 1; d < 16; d <<= 1) {
      unsigned o = __shfl_up(vs, d);
      if (lane >= d) vs += o;
    }
    if (tid < 16) wsum[tid] = vs - c16;
  }
  __syncthreads();
  unsigned running = wsum[wid] + v - mysum;
#pragma unroll
  for (int i = 0; i < 5; i++) {
    unsigned c = hist[base5 + i];
    hist[base5 + i] = running;
    running += c;
  }
  __syncthreads();

  // scatter into bin slots
  for (unsigned p = tid; p < total; p += 1024) {
    u64 key = cand[p];
    unsigned bin = (0x3F800000u - (unsigned)(key >> 32) - 1u) >> 2;
    if (bin >= NB2) bin = NB2 - 1;
    unsigned pos = atomicAdd(&hist[bin], 1u);
    if (pos < CAP2) outk[pos] = key;
  }
  __syncthreads();

  // insertion sort ties within each bin (full u64 key -> deterministic order).
  // Bins starting at lo >= NK cannot affect the top-NK output -> skipped.
  for (int bin = tid; bin < NB2; bin += 1024) {
    unsigned hi = hist[bin];
    unsigned lo = bin ? hist[bin - 1] : 0u;
    if (lo >= NK) continue;
    if (hi > CAP2) hi = CAP2;
    if (lo > CAP2) lo = CAP2;
    if (hi > lo + 1) {
      for (unsigned i2 = lo + 1; i2 < hi; i2++) {
        u64 kx = outk[i2];
        int j = (int)i2 - 1;
        while (j >= (int)lo && outk[j] < kx) { outk[j + 1] = outk[j]; j--; }
        outk[j + 1] = kx;
      }
    }
  }
  __syncthreads();

  // ---- phase B: decode top-n + per-class NMS over overlaid LDS ----
  int n = (int)total; if (n > NK) n = NK;
  float4* bo = (float4*)S;                              // [0, 16000)
  unsigned short* llab = (unsigned short*)(S + 16000);  // [16000, 18000)
  unsigned short* sidx = (unsigned short*)(S + 18000);  // [18000, 20000)
  unsigned char* live = (unsigned char*)(S + 20000);    // [20000, 21000)
  u64* clsbits = (u64*)(S + 21008);                     // [21008, 32528) 90x16
  u64* nmsmask = (u64*)(S + 32536);                     // [32536, 78616) 90x64
  // clsbits/bo/llab/sidx/live sit in dead cand[]; nmsmask additionally
  // overlays outk[] but is only written AFTER decode consumed outk.

  float H = (float)isz[b * 2 + 0];
  float W = (float)isz[b * 2 + 1];
  float scale = (float)iszo[b * 2 + 0] / H;
  float offmul = fmaxf(W, H) + 1.0f;
  for (int i = tid; i < NC * 16; i += 1024) clsbits[i] = 0ULL;
  for (int k = tid; k < n; k += 1024) {
    u64 key = outk[k];
    float sc = __uint_as_float((unsigned)(key >> 32));
    unsigned idx = 0xFFFFu - (unsigned)((key >> 16) & 0xFFFFull);
    int lab = (int)(key & 0xFFFFull);
    float raw[4];
    float4 rg = ((const float4*)regs)[(size_t)b * NN + idx];
    float4 an = ((const float4*)anch)[idx];
    decode_box(rg, an, W, H, raw);
    float off = (float)lab * offmul;
    bo[k] = make_float4(raw[0] + off, raw[1] + off, raw[2] + off, raw[3] + off);
    llab[k] = (unsigned short)lab;
    live[k] = 1;
    int g = b * NK + k;
    float* o5 = out + (size_t)g * 5;
    o5[0] = raw[0] * scale; o5[1] = raw[1] * scale;
    o5[2] = raw[2] * scale; o5[3] = raw[3] * scale;
    o5[4] = sc;
    out[(size_t)NB * NK * 5 + g] = (float)lab;
  }
  __syncthreads();  // outk fully consumed; clsbits zeroed

  // per-class membership bitmaps (k ascending == score descending)
  for (int k = tid; k < n; k += 1024)
    atomicOr(&clsbits[(int)llab[k] * 16 + (k >> 6)], 1ULL << (k & 63));
  __syncthreads();

  if (tid < NC) {
    unsigned cnt = 0;
#pragma unroll
    for (int w = 0; w < 16; w++) cnt += (unsigned)__popcll(clsbits[tid * 16 + w]);
    lcnt[tid] = (int)cnt;
  }
  __syncthreads();
  // parallel exclusive scan of 90 class counts via wave 0, 2 bins/lane
  // (was serial tid==0 loop: 90 dependent LDS round trips ~3-4us)
  if (tid < 64) {
    int i0 = 2 * tid, i1 = 2 * tid + 1;
    int c0 = (i0 < NC) ? lcnt[i0] : 0;
    int c1 = (i1 < NC) ? lcnt[i1] : 0;
    int s2 = c0 + c1;
    int vs = s2;
    for (int d = 1; d < 64; d <<= 1) {
      int o = __shfl_up(vs, d);
      if (lane >= d) vs += o;
    }
    int excl = vs - s2;
    if (i0 < NC) lofs[i0] = excl;
    if (i1 < NC) lofs[i1] = excl + c0;
    if (i1 == NC - 1) lofs[NC] = vs;   // inclusive total through class 89
  }
  __syncthreads();

  // deterministic rank placement: sidx buckets sorted ascending k, no sort
  for (int k = tid; k < n; k += 1024) {
    int lab = (int)llab[k];
    const u64* cb = &clsbits[lab * 16];
    int w0 = k >> 6;
    unsigned pos = 0;
    for (int w = 0; w < w0; w++) pos += (unsigned)__popcll(cb[w]);
    pos += (unsigned)__popcll(cb[w0] & ((1ULL << (k & 63)) - 1ULL));
    sidx[lofs[lab] + pos] = (unsigned short)k;
  }
  __syncthreads();

  // pair IoU, one suppression row per thread (1024-wide parallel).
  // sidx[p] < sidx[q] for p<q in a bucket -> verbatim i<j operand order.
  float thr = *nthr_p;
  for (int p = tid; p < n; p += 1024) {
    int ki = (int)sidx[p];
    int lab = (int)llab[ki];
    int s = lofs[lab], e = lofs[lab + 1];
    int r = p - s;
    if (r < 64) {
      u64 mask = 0ULL;
      float4 Bb = bo[ki];
      float x0 = Bb.x, y0 = Bb.y, x1 = Bb.z, y1 = Bb.w;
      float ai = (x1 - x0) * (y1 - y0);
      int qe = e; if (qe > s + 64) qe = s + 64;
      for (int q = p + 1; q < qe; q++) {
        int kj = (int)sidx[q];
        float4 Cc = bo[kj];
        float aj = (Cc.z - Cc.x) * (Cc.w - Cc.y);
        float ltx = fmaxf(x0, Cc.x), lty = fmaxf(y0, Cc.y);
        float rbx = fminf(x1, Cc.z), rby = fminf(y1, Cc.w);
        float ww = fmaxf(rbx - ltx, 0.f), hh = fmaxf(rby - lty, 0.f);
        float inter = ww * hh;
        float den = ((ai + aj) - inter) + 1e-9f;
        float iou = inter / den;
        if (iou > thr) mask |= 1ULL << (q - s);
      }
      nmsmask[lab * 64 + r] = mask;   // row owned by exactly this thread
    }
  }
  __syncthreads();

  // per-class greedy chain: O(m) dependent LDS reads, register rem
  if (tid < NC) {
    int s = lofs[tid], e = lofs[tid + 1], m = e - s;
    if (m <= 64) {
      u64 rem = 0ULL;
      for (int r = 0; r < m; r++)
        if (!((rem >> r) & 1ULL)) rem |= nmsmask[tid * 64 + r];
      for (int r = 0; r < m; r++)
        live[(int)sidx[s + r]] = (unsigned char)(1ULL ^ ((rem >> r) & 1ULL));
    } else {
      // exact fallback (bucket > 64: statistically unreachable here)
      for (int r = 0; r < m; r++) live[(int)sidx[s + r]] = 1;
      for (int i = s; i < e; i++) {
        int ki = (int)sidx[i];
        if (!live[ki]) continue;
        float4 Bb = bo[ki];
        float x0 = Bb.x, y0 = Bb.y, x1 = Bb.z, y1 = Bb.w;
        float ai = (x1 - x0) * (y1 - y0);
        for (int j = i + 1; j < e; j++) {
          int kj = (int)sidx[j];
          if (!live[kj]) continue;
          float4 Cc = bo[kj];
          float aj = (Cc.z - Cc.x) * (Cc.w - Cc.y);
          float ltx = fmaxf(x0, Cc.x), lty = fmaxf(y0, Cc.y);
          float rbx = fminf(x1, Cc.z), rby = fminf(y1, Cc.w);
          float ww = fmaxf(rbx - ltx, 0.f), hh = fmaxf(rby - lty, 0.f);
          float inter = ww * hh;
          float den = ((ai + aj) - inter) + 1e-9f;
          float iou = inter / den;
          if (iou > thr) live[kj] = 0;
        }
      }
    }
  }
  __syncthreads();

  for (int k = tid; k < NK; k += 1024) {
    int g = b * NK + k;
    int keep = (k < n) ? (int)live[k] : 0;
    if (keep) {
      out[(size_t)NB * NK * 6 + g] = 1.0f;
    } else {
      float* o5 = out + (size_t)g * 5;
      o5[0] = 0.f; o5[1] = 0.f; o5[2] = 0.f; o5[3] = 0.f; o5[4] = 0.f;
      out[(size_t)NB * NK * 5 + g] = -1.0f;
      out[(size_t)NB * NK * 6 + g] = 0.0f;
    }
  }
}

extern "C" void kernel_launch(void* const* d_in, const int* in_sizes, int n_in,
                              void* d_out, int out_size, void* d_ws, size_t ws_size,
                              hipStream_t stream) {
  const float* cls = (const float*)d_in[0];
  const float* regs = (const float*)d_in[1];
  const float* anch = (const float*)d_in[2];
  const int* isz = (const int*)d_in[3];
  const int* iszo = (const int*)d_in[4];
  const float* sthr = (const float*)d_in[5];
  const float* nthr = (const float*)d_in[6];
  float* out = (float*)d_out;

  char* p = (char*)d_ws;
  auto alloc = [&](size_t bytes) {
    char* r = p;
    p += (bytes + 255) & ~(size_t)255;
    return r;
  };
  u64* cseg = (u64*)alloc((size_t)NB * NSEG * SA * 8);       // 3.15 MB
  unsigned* segcnt = (unsigned*)alloc((size_t)NB * NSEG * 4);

  hipLaunchKernelGGL(k_score, dim3(NSEG, NB), dim3(768), 0, stream,
                     cls, sthr, cseg, segcnt);
  hipLaunchKernelGGL(k_worker, dim3(NB), dim3(1024), 0, stream,
                     cseg, segcnt, regs, anch, isz, iszo, nthr, out);
}